// Round 6
// baseline (739.087 us; speedup 1.0000x reference)
//
#include <hip/hip_runtime.h>
#include <hip/hip_bf16.h>

typedef __attribute__((ext_vector_type(8))) short short8;
typedef __attribute__((ext_vector_type(4))) short short4v;
typedef __attribute__((ext_vector_type(4))) float floatx4;
typedef __hip_bfloat16 bf16;

__device__ __forceinline__ short f2bs(float f) {
  bf16 h = __float2bfloat16(f);
  return __builtin_bit_cast(short, h);
}
__device__ __forceinline__ float s2f(short s) {  // bf16 bits -> fp32
  unsigned u = ((unsigned)(unsigned short)s) << 16;
  return __builtin_bit_cast(float, u);
}

// ---------------- combined weights (t2 folded in) ----------------
// Wc[branch*512 + qkv*160 + oc][c] = ln_w[c] * sum_k proj[oc][k]*conv_w[branch*160+k][c]
// bc[..] = proj.b[oc] + sum_k proj[oc][k]*(conv_b[bk] + sum_c conv_w[bk][c]*ln_b[c])
struct WcArgs {
  const float* conv_w;
  const float* conv_b;
  const float* ln_w;
  const float* ln_b;
  const float* pw[6];
  const float* pb[6];
  bf16* Wc;
  float* bc;
};

__global__ void k_wc(WcArgs a) {
  int o = blockIdx.x, t = threadIdx.x;
  int branch = o >> 9, r = o & 511;
  bf16* wrow = a.Wc + (size_t)o * 320;
  if (r >= 480) {  // pad rows (BM=256 over M=480) must be zero
    for (int c = t; c < 320; c += 64) wrow[c] = __float2bfloat16(0.f);
    if (t == 0) a.bc[o] = 0.f;
    return;
  }
  int qkv = r / 160, oc = r % 160;
  const float* pw = a.pw[branch * 3 + qkv];
  const float* pb = a.pb[branch * 3 + qkv];
  float scale = (qkv == 0) ? 0.17677669529663687f : 1.f;  // 1/sqrt(32) folded into q
  for (int c = t; c < 320; c += 64) {
    float acc = 0.f;
    for (int k = 0; k < 160; ++k)
      acc += pw[oc * 160 + k] * a.conv_w[(branch * 160 + k) * 320 + c];
    wrow[c] = __float2bfloat16(acc * a.ln_w[c] * scale);
  }
  float bacc = 0.f;
  for (int k = t; k < 160; k += 64) {           // t2 inline: tiny redundant work
    int bk = branch * 160 + k;
    float t2k = a.conv_b[bk];
    const float* cwrow = a.conv_w + (size_t)bk * 320;
    for (int c = 0; c < 320; ++c) t2k += cwrow[c] * a.ln_b[c];
    bacc += pw[oc * 160 + k] * t2k;
  }
  #pragma unroll
  for (int off = 32; off; off >>= 1) bacc += __shfl_down(bacc, off);
  if (t == 0) a.bc[o] = (bacc + pb[oc]) * scale;
}

// ---------------- LN stats + normalize + transpose:  XnT[b][p][c] ----------------
// BOTH batches in one 2048-block launch. 64 pixels/block, 4 waves; wave w owns
// channels [w*80, w*80+80). Register-cached input (80 f32/thread) -> single HBM pass.
__global__ void k_xnt(const float* __restrict__ x, bf16* __restrict__ XnT_all) {
  __shared__ float red[2][4][64];
  int b = blockIdx.x >> 10, blk = blockIdx.x & 1023;
  int t = threadIdx.x, w = t >> 6, l = t & 63;
  int pl = blk * 64 + l;                             // pixel within batch b (lane = pixel)
  const float* xb = x + (size_t)b * 320 * 65536 + pl;
  float v[80];
  float sum = 0.f, ss = 0.f;
  #pragma unroll
  for (int i = 0; i < 80; ++i) {
    v[i] = xb[(size_t)(w * 80 + i) * 65536];
    sum += v[i]; ss += v[i] * v[i];
  }
  red[0][w][l] = sum; red[1][w][l] = ss;
  __syncthreads();
  float tsum = red[0][0][l] + red[0][1][l] + red[0][2][l] + red[0][3][l];
  float tss  = red[1][0][l] + red[1][1][l] + red[1][2][l] + red[1][3][l];
  float mean = tsum * (1.f / 320.f);
  float var = tss * (1.f / 320.f) - mean * mean;
  float rstd = rsqrtf(var + 1e-5f);
  float sh = -mean * rstd;
  short8* orow = (short8*)(XnT_all + (size_t)b * 20971520 + (size_t)pl * 320 + w * 80);
  #pragma unroll
  for (int cc = 0; cc < 10; ++cc) {
    short8 o;
    #pragma unroll
    for (int j = 0; j < 8; ++j)
      o[j] = f2bs(fmaf(v[cc * 8 + j], rstd, sh));
    orow[cc] = o;
  }
}

// ---------------- GEMM: Y[b][br][qkv][p][oc] = Wc[o][:] . XnT[b][p][:] + bc[o] ----------------
// BOTH batches + branches in one 4096-block launch. M=1024 (2br x 512pad), N=65536, K=320.
// XCD-chunked swizzle puts mb=0..3 of one nb adjacent on one XCD -> B-tile L2 reuse.
__launch_bounds__(512)
__global__ void k_gemm(const bf16* __restrict__ Wc, const float* __restrict__ bc,
                       const bf16* __restrict__ XnT_all, bf16* __restrict__ Y_all) {
  __shared__ short As[256 * 40];   // 256 rows x 32k, padded pitch 40 shorts (80B)
  __shared__ short Bs[128 * 40];
  int lin = blockIdx.x;
  int batch = lin >> 11, lin2 = lin & 2047;
  int swz = (lin2 & 7) * 256 + (lin2 >> 3);   // bijective: 2048 % 8 == 0
  int nb = swz >> 2, mb = swz & 3;            // nb 0..511, mb 0..3
  const bf16* XnT = XnT_all + (size_t)batch * 20971520;
  bf16* Yout = Y_all + (size_t)batch * 62914560;
  int t = threadIdx.x, wv = t >> 6, l = t & 63;
  int wm = wv >> 1, wn = wv & 1;   // 4x2 waves, 64x64 C-tile per wave
  floatx4 acc[4][4];
  #pragma unroll
  for (int i = 0; i < 4; ++i)
    #pragma unroll
    for (int j = 0; j < 4; ++j) acc[i][j] = floatx4{0.f, 0.f, 0.f, 0.f};

  for (int k0 = 0; k0 < 320; k0 += 32) {
    __syncthreads();
    #pragma unroll
    for (int i = 0; i < 2; ++i) {            // stage A: 256 rows x 64B
      int u = t + i * 512;
      int r = u >> 2, ch = u & 3;
      short8 v = *(const short8*)(Wc + (size_t)(mb * 256 + r) * 320 + k0 + ch * 8);
      *(short8*)(As + r * 40 + ch * 8) = v;
    }
    {                                        // stage B: 128 pixel-rows x 64B
      int n = t >> 2, ch = t & 3;
      short8 v = *(const short8*)(XnT + (size_t)(nb * 128 + n) * 320 + k0 + ch * 8);
      *(short8*)(Bs + n * 40 + ch * 8) = v;
    }
    __syncthreads();
    short8 af[4], bfr[4];
    #pragma unroll
    for (int mt = 0; mt < 4; ++mt)
      af[mt] = *(const short8*)(As + (wm * 64 + mt * 16 + (l & 15)) * 40 + (l >> 4) * 8);
    #pragma unroll
    for (int nt = 0; nt < 4; ++nt)
      bfr[nt] = *(const short8*)(Bs + (wn * 64 + nt * 16 + (l & 15)) * 40 + (l >> 4) * 8);
    #pragma unroll
    for (int mt = 0; mt < 4; ++mt)
      #pragma unroll
      for (int nt = 0; nt < 4; ++nt)
        acc[mt][nt] = __builtin_amdgcn_mfma_f32_16x16x32_bf16(af[mt], bfr[nt], acc[mt][nt], 0, 0, 0);
  }

  #pragma unroll
  for (int mt = 0; mt < 4; ++mt) {
    int ob = mb * 256 + wm * 64 + mt * 16 + (l >> 4) * 4;  // global W-row (0..1023)
    int br = ob >> 9, rr = ob & 511;
    if (rr >= 480) continue;
    int qkv = rr / 160, oc = rr % 160;
    bf16* yb = Yout + (size_t)br * 31457280 + (size_t)qkv * 10485760;
    floatx4 bias = *(const floatx4*)(bc + ob);
    #pragma unroll
    for (int nt = 0; nt < 4; ++nt) {
      int pl = nb * 128 + wn * 64 + nt * 16 + (l & 15);
      short4v o;
      #pragma unroll
      for (int r = 0; r < 4; ++r) o[r] = f2bs(acc[mt][nt][r] + bias[r]);
      *(short4v*)(yb + (size_t)pl * 160 + oc) = o;
    }
  }
}

// ---------------- attention: one WG per (batch, branch, seq, head); qb looped ----------------
// BOTH batches in one 5120-block launch. K/V staged ONCE per (s,head).
// S^T = K.Q^T, exp'd P packs contiguously, online rowsum, O = P.V / rowsum.
__launch_bounds__(256, 2)
__global__ void k_attn(const bf16* __restrict__ Y_all, float* __restrict__ out,
                       bf16* __restrict__ av_all) {
  __shared__ short Ks[256 * 40];    // K [pos][32ch], pitch 40
  __shared__ short Vt[32 * 264];    // V^T [ch][256pos], pitch 264
  __shared__ short Ps[64 * 264];    // exp(S) [qrow][256pos], pitch 264
  __shared__ float rsum[64];
  int lin = blockIdx.x;
  int batch = (lin >= 2560) ? 1 : 0;
  int lin2 = lin - batch * 2560;
  int vb = (lin2 >= 1280) ? 1 : 0;
  int r2 = lin2 - vb * 1280;        // 0..1279 = head*256 + s
  int head = r2 >> 8, s = r2 & 255;
  const bf16* Yq = Y_all + (size_t)batch * 62914560 + (size_t)vb * 31457280;
  const bf16* Yk = Yq + 10485760;
  const bf16* Yv = Yk + 10485760;
  float* outF = out + (size_t)batch * 10485760;
  bf16* av = av_all + (size_t)batch * 10485760;
  int t = threadIdx.x, wv = t >> 6, l = t & 63;

  #pragma unroll
  for (int i = 0; i < 4; ++i) {     // stage K
    int u = t + i * 256;
    int pos = u >> 2, ch = u & 3;
    size_t pix = vb ? ((size_t)pos * 256 + s) : ((size_t)s * 256 + pos);
    short8 kv = *(const short8*)(Yk + pix * 160 + head * 32 + ch * 8);
    *(short8*)(Ks + pos * 40 + ch * 8) = kv;
  }
  #pragma unroll
  for (int i = 0; i < 2; ++i) {     // stage V transposed: pos-pairs, packed b32 writes
    int u = t + i * 256;
    int pp = u >> 2, ch = u & 3;    // pp: pos pair 0..127
    int pos0 = pp * 2;
    size_t pix0 = vb ? ((size_t)pos0 * 256 + s) : ((size_t)s * 256 + pos0);
    size_t pix1 = vb ? ((size_t)(pos0 + 1) * 256 + s) : ((size_t)s * 256 + pos0 + 1);
    short8 v0 = *(const short8*)(Yv + pix0 * 160 + head * 32 + ch * 8);
    short8 v1 = *(const short8*)(Yv + pix1 * 160 + head * 32 + ch * 8);
    #pragma unroll
    for (int j = 0; j < 8; ++j) {
      unsigned pack = (unsigned)(unsigned short)v0[j] | ((unsigned)(unsigned short)v1[j] << 16);
      *(unsigned*)(Vt + (ch * 8 + j) * 264 + pos0) = pack;   // pos0 even -> 4B aligned
    }
  }
  __syncthreads();

  for (int qb = 0; qb < 4; ++qb) {
    // Q B-fragment straight from global (L2-hot): lane holds Q[qrow=l&15][ch=(l>>4)*8+j]
    int qrow = qb * 64 + wv * 16 + (l & 15);
    size_t qpix = vb ? ((size_t)qrow * 256 + s) : ((size_t)s * 256 + qrow);
    short8 qf = *(const short8*)(Yq + qpix * 160 + head * 32 + (l >> 4) * 8);

    float psum = 0.f;
    #pragma unroll
    for (int mt = 0; mt < 16; ++mt) {  // S^T strip: 256 pos x 16 qrows per wave
      short8 kf = *(const short8*)(Ks + (mt * 16 + (l & 15)) * 40 + (l >> 4) * 8);
      floatx4 st = __builtin_amdgcn_mfma_f32_16x16x32_bf16(kf, qf, floatx4{0.f, 0.f, 0.f, 0.f}, 0, 0, 0);
      short4v pv;
      #pragma unroll
      for (int r = 0; r < 4; ++r) {    // scores are tiny (weights*0.02): exp w/o max-sub is safe
        float e = __expf(st[r]);
        psum += e;
        pv[r] = f2bs(e);
      }
      // lane holds S^T[pos=mt*16+(l>>4)*4+r][qrow=wv*16+(l&15)] -> contiguous 4-pos pack
      *(short4v*)(Ps + (wv * 16 + (l & 15)) * 264 + mt * 16 + (l >> 4) * 4) = pv;
    }
    psum += __shfl_xor(psum, 16);
    psum += __shfl_xor(psum, 32);
    if (l < 16) rsum[wv * 16 + l] = psum;
    __syncthreads();

    floatx4 oacc[2] = {floatx4{0.f, 0.f, 0.f, 0.f}, floatx4{0.f, 0.f, 0.f, 0.f}};
    #pragma unroll
    for (int kt = 0; kt < 8; ++kt) {
      short8 pf = *(const short8*)(Ps + (wv * 16 + (l & 15)) * 264 + kt * 32 + (l >> 4) * 8);
      #pragma unroll
      for (int nt = 0; nt < 2; ++nt) {
        short8 vf = *(const short8*)(Vt + (nt * 16 + (l & 15)) * 264 + kt * 32 + (l >> 4) * 8);
        oacc[nt] = __builtin_amdgcn_mfma_f32_16x16x32_bf16(pf, vf, oacc[nt], 0, 0, 0);
      }
    }
    floatx4 rs = *(const floatx4*)(rsum + wv * 16 + (l >> 4) * 4);
    #pragma unroll
    for (int nt = 0; nt < 2; ++nt) {
      int ch = head * 32 + nt * 16 + (l & 15);
      int p0 = qb * 64 + wv * 16 + (l >> 4) * 4;  // 4 consecutive positions
      if (vb == 0) {
        floatx4 o;
        #pragma unroll
        for (int r = 0; r < 4; ++r) o[r] = oacc[nt][r] / rs[r];
        *(floatx4*)(outF + (size_t)ch * 65536 + s * 256 + p0) = o;   // out[b][ch][h=s][w], fp32
      } else {
        short4v o;
        #pragma unroll
        for (int r = 0; r < 4; ++r) o[r] = f2bs(oacc[nt][r] / rs[r]);
        *(short4v*)(av + (size_t)s * 40960 + ch * 256 + p0) = o;     // av[s=w][ch][h], bf16
      }
    }
    __syncthreads();   // protect Ps/rsum reuse by next qb iteration
  }
}

// ---------------- v-branch layout fix: out[2+b][oc][h][w] = av[b][w][oc][h], bf16 -> fp32 ----------------
__global__ void k_trans(const bf16* __restrict__ av_all, float* __restrict__ out) {
  __shared__ short tile[64 * 68];
  int oc = blockIdx.x;
  int b = blockIdx.y >> 2, w0 = (blockIdx.y & 3) * 64, h0 = blockIdx.z * 64;
  const bf16* av = av_all + (size_t)b * 10485760;
  float* outb = out + (size_t)(2 + b) * 10485760;
  int t = threadIdx.x;
  #pragma unroll
  for (int i = 0; i < 2; ++i) {
    int u = t + i * 256;
    int w_i = u >> 3, hc = u & 7;
    short8 v = *(const short8*)(av + (size_t)(w0 + w_i) * 40960 + oc * 256 + h0 + hc * 8);
    short4v lo = {v[0], v[1], v[2], v[3]}, hi = {v[4], v[5], v[6], v[7]};
    *(short4v*)(tile + w_i * 68 + hc * 8) = lo;
    *(short4v*)(tile + w_i * 68 + hc * 8 + 4) = hi;
  }
  __syncthreads();
  #pragma unroll
  for (int i = 0; i < 2; ++i) {
    int u = t + i * 256;
    int h_i = u >> 3, wc = u & 7;
    float* orow = outb + (size_t)oc * 65536 + (h0 + h_i) * 256 + w0 + wc * 8;
    floatx4 o0, o1;
    #pragma unroll
    for (int j = 0; j < 4; ++j) o0[j] = s2f(tile[(wc * 8 + j) * 68 + h_i]);
    #pragma unroll
    for (int j = 0; j < 4; ++j) o1[j] = s2f(tile[(wc * 8 + 4 + j) * 68 + h_i]);
    *(floatx4*)(orow) = o0;
    *(floatx4*)(orow + 4) = o1;
  }
}

extern "C" void kernel_launch(void* const* d_in, const int* in_sizes, int n_in,
                              void* d_out, int out_size, void* d_ws, size_t ws_size,
                              hipStream_t stream) {
  (void)in_sizes; (void)n_in; (void)out_size; (void)ws_size;
  const float* x      = (const float*)d_in[0];
  const float* ln_w   = (const float*)d_in[1];
  const float* ln_b   = (const float*)d_in[2];
  const float* conv_w = (const float*)d_in[3];
  const float* conv_b = (const float*)d_in[4];
  float* outF = (float*)d_out;

  char* ws = (char*)d_ws;
  bf16*  Wc  = (bf16*)ws;                                   // 2*512*320 bf16 = 655360 B
  float* bc  = (float*)(ws + 655360);                       // 1024 f32 (pad to 660736)
  bf16*  XnT = (bf16*)(ws + 660736);                        // 2 * 41943040 B
  bf16*  Y   = (bf16*)(ws + 660736 + 83886080ULL);          // 2 * 125829120 B
  bf16*  av  = (bf16*)(ws + 660736 + 83886080ULL + 251658240ULL);  // 2 * 20971520 B

  WcArgs wa;
  wa.conv_w = conv_w; wa.conv_b = conv_b; wa.ln_w = ln_w; wa.ln_b = ln_b;
  wa.Wc = Wc; wa.bc = bc;
  for (int br = 0; br < 2; ++br)
    for (int q = 0; q < 3; ++q) {
      wa.pw[br * 3 + q] = (const float*)d_in[5 + br * 6 + q * 2];
      wa.pb[br * 3 + q] = (const float*)d_in[6 + br * 6 + q * 2];
    }
  k_wc<<<1024, 64, 0, stream>>>(wa);

  k_xnt<<<2048, 256, 0, stream>>>(x, XnT);
  k_gemm<<<4096, 512, 0, stream>>>(Wc, bc, XnT, Y);
  k_attn<<<5120, 256, 0, stream>>>(Y, outF, av);
  k_trans<<<dim3(160, 8, 4), 256, 0, stream>>>(av, outF);
}

// Round 7
// 651.007 us; speedup vs baseline: 1.1353x; 1.1353x over previous
//
#include <hip/hip_runtime.h>
#include <hip/hip_bf16.h>

typedef __attribute__((ext_vector_type(8))) short short8;
typedef __attribute__((ext_vector_type(4))) short short4v;
typedef __attribute__((ext_vector_type(4))) float floatx4;
typedef __hip_bfloat16 bf16;

__device__ __forceinline__ short f2bs(float f) {
  bf16 h = __float2bfloat16(f);
  return __builtin_bit_cast(short, h);
}
__device__ __forceinline__ float s2f(short s) {  // bf16 bits -> fp32
  unsigned u = ((unsigned)(unsigned short)s) << 16;
  return __builtin_bit_cast(float, u);
}
__device__ __forceinline__ void gload16(const void* g, void* l) {  // 16B/lane global->LDS DMA
  __builtin_amdgcn_global_load_lds(
      (const __attribute__((address_space(1))) unsigned int*)g,
      (__attribute__((address_space(3))) unsigned int*)l, 16, 0, 0);
}

// ---------------- t2[k] = conv_b[k] + sum_c conv_w[k][c]*ln_b[c] ----------------
__global__ void k_t2(const float* __restrict__ conv_w, const float* __restrict__ conv_b,
                     const float* __restrict__ ln_b, float* __restrict__ t2) {
  int k = blockIdx.x, t = threadIdx.x;
  float s = 0.f;
  for (int c = t; c < 320; c += 64) s += conv_w[k * 320 + c] * ln_b[c];
  #pragma unroll
  for (int off = 32; off; off >>= 1) s += __shfl_down(s, off);
  if (t == 0) t2[k] = s + conv_b[k];
}

// ---------------- combined weights ----------------
struct WcArgs {
  const float* conv_w;
  const float* ln_w;
  const float* t2;
  const float* pw[6];
  const float* pb[6];
  bf16* Wc;
  float* bc;
};

__global__ void k_wc(WcArgs a) {
  int o = blockIdx.x, t = threadIdx.x;
  int branch = o >> 9, r = o & 511;
  bf16* wrow = a.Wc + (size_t)o * 320;
  if (r >= 480) {  // pad rows (BM=256 over M=480) must be zero
    for (int c = t; c < 320; c += 64) wrow[c] = __float2bfloat16(0.f);
    if (t == 0) a.bc[o] = 0.f;
    return;
  }
  int qkv = r / 160, oc = r % 160;
  const float* pw = a.pw[branch * 3 + qkv];
  const float* pb = a.pb[branch * 3 + qkv];
  float scale = (qkv == 0) ? 0.17677669529663687f : 1.f;  // 1/sqrt(32) folded into q
  for (int c = t; c < 320; c += 64) {
    float acc = 0.f;
    for (int k = 0; k < 160; ++k)
      acc += pw[oc * 160 + k] * a.conv_w[(branch * 160 + k) * 320 + c];
    wrow[c] = __float2bfloat16(acc * a.ln_w[c] * scale);
  }
  float bacc = 0.f;
  for (int k = t; k < 160; k += 64) bacc += pw[oc * 160 + k] * a.t2[branch * 160 + k];
  #pragma unroll
  for (int off = 32; off; off >>= 1) bacc += __shfl_down(bacc, off);
  if (t == 0) a.bc[o] = (bacc + pb[oc]) * scale;
}

// ---------------- LN stats + normalize + transpose:  XnT[p][c] = (x[c][p]-mu)*rstd ----------------
// 64 pixels/block, 4 waves; wave w owns channels [w*80, w*80+80). Grid 1024.
// Register-cached input (80 f32/thread) -> single HBM pass.
__global__ void k_xnt(const float* __restrict__ x, bf16* __restrict__ XnT, int b) {
  __shared__ float red[2][4][64];
  int t = threadIdx.x, w = t >> 6, l = t & 63;
  int pl = blockIdx.x * 64 + l;                      // pixel within batch b (lane = pixel)
  const float* xb = x + (size_t)b * 320 * 65536 + pl;
  float v[80];
  float sum = 0.f, ss = 0.f;
  #pragma unroll
  for (int i = 0; i < 80; ++i) {
    v[i] = xb[(size_t)(w * 80 + i) * 65536];
    sum += v[i]; ss += v[i] * v[i];
  }
  red[0][w][l] = sum; red[1][w][l] = ss;
  __syncthreads();
  float tsum = red[0][0][l] + red[0][1][l] + red[0][2][l] + red[0][3][l];
  float tss  = red[1][0][l] + red[1][1][l] + red[1][2][l] + red[1][3][l];
  float mean = tsum * (1.f / 320.f);
  float var = tss * (1.f / 320.f) - mean * mean;
  float rstd = rsqrtf(var + 1e-5f);
  float sh = -mean * rstd;
  short8* orow = (short8*)(XnT + (size_t)pl * 320 + w * 80);  // 80 shorts = 160B, 16B-aligned
  #pragma unroll
  for (int cc = 0; cc < 10; ++cc) {
    short8 o;
    #pragma unroll
    for (int j = 0; j < 8; ++j)
      o[j] = f2bs(fmaf(v[cc * 8 + j], rstd, sh));
    orow[cc] = o;
  }
}

// ---------------- GEMM: Y[br][qkv][p][oc] = Wc[o][:] . XnT[p][:] + bc[o] ----------------
// Both branches, one batch per launch. M=1024 (2br x 512pad), N=65536, K=320.
// v4: global_load_lds width-16 staging into LINEAR LDS (64B rows, no pad) — removes
// the reg round-trip + staging VALU that held MfmaUtil at 19%. m104 rule satisfied:
// per wave, LDS dest = uniform base + lane*16 ((l>>2)*64 + (l&3)*16 == 16*l).
__launch_bounds__(512)
__global__ void k_gemm(const bf16* __restrict__ Wc, const float* __restrict__ bc,
                       const bf16* __restrict__ XnT, bf16* __restrict__ Yout) {
  __shared__ short As[256 * 32];   // 256 rows x 64B, linear
  __shared__ short Bs[128 * 32];   // 128 rows x 64B, linear
  int lin = blockIdx.x;
  int swz = (lin & 7) * 256 + (lin >> 3);   // bijective: 2048 % 8 == 0
  int nb = swz >> 2, mb = swz & 3;          // nb 0..511, mb 0..3
  int t = threadIdx.x, wv = t >> 6, l = t & 63;
  int wm = wv >> 1, wn = wv & 1;   // 4x2 waves, 64x64 C-tile per wave
  floatx4 acc[4][4];
  #pragma unroll
  for (int i = 0; i < 4; ++i)
    #pragma unroll
    for (int j = 0; j < 4; ++j) acc[i][j] = floatx4{0.f, 0.f, 0.f, 0.f};

  int lr = l >> 2, lc = l & 3;     // lane row-within-16 / 16B chunk
  for (int k0 = 0; k0 < 320; k0 += 32) {
    __syncthreads();               // previous iter's frag reads done before overwrite
    #pragma unroll
    for (int i = 0; i < 2; ++i) {  // stage A: wave wv covers rows wv*32+i*16 .. +15
      int rb = wv * 32 + i * 16;
      gload16(Wc + (size_t)(mb * 256 + rb + lr) * 320 + k0 + lc * 8, As + rb * 32);
    }
    {                              // stage B: wave wv covers rows wv*16 .. +15
      int rb = wv * 16;
      gload16(XnT + (size_t)(nb * 128 + rb + lr) * 320 + k0 + lc * 8, Bs + rb * 32);
    }
    asm volatile("s_waitcnt vmcnt(0)" ::: "memory");
    __syncthreads();
    short8 af[4], bfr[4];
    #pragma unroll
    for (int mt = 0; mt < 4; ++mt)
      af[mt] = *(const short8*)(As + (wm * 64 + mt * 16 + (l & 15)) * 32 + (l >> 4) * 8);
    #pragma unroll
    for (int nt = 0; nt < 4; ++nt)
      bfr[nt] = *(const short8*)(Bs + (wn * 64 + nt * 16 + (l & 15)) * 32 + (l >> 4) * 8);
    #pragma unroll
    for (int mt = 0; mt < 4; ++mt)
      #pragma unroll
      for (int nt = 0; nt < 4; ++nt)
        acc[mt][nt] = __builtin_amdgcn_mfma_f32_16x16x32_bf16(af[mt], bfr[nt], acc[mt][nt], 0, 0, 0);
  }

  #pragma unroll
  for (int mt = 0; mt < 4; ++mt) {
    int ob = mb * 256 + wm * 64 + mt * 16 + (l >> 4) * 4;  // global W-row (0..1023)
    int br = ob >> 9, rr = ob & 511;
    if (rr >= 480) continue;
    int qkv = rr / 160, oc = rr % 160;
    bf16* yb = Yout + (size_t)br * 31457280 + (size_t)qkv * 10485760;
    floatx4 bias = *(const floatx4*)(bc + ob);
    #pragma unroll
    for (int nt = 0; nt < 4; ++nt) {
      int pl = nb * 128 + wn * 64 + nt * 16 + (l & 15);
      short4v o;
      #pragma unroll
      for (int r = 0; r < 4; ++r) o[r] = f2bs(acc[mt][nt][r] + bias[r]);
      *(short4v*)(yb + (size_t)pl * 160 + oc) = o;
    }
  }
}

// ---------------- attention: one WG per (branch, seq, head); qb looped ----------------
// K/V staged ONCE per (s,head); both branches in one 2560-block launch.
// S^T = K.Q^T, exp'd P packs contiguously, online rowsum, O = P.V / rowsum.
__launch_bounds__(256, 2)
__global__ void k_attn(const bf16* __restrict__ Y, float* __restrict__ outF,
                       bf16* __restrict__ av) {
  __shared__ short Ks[256 * 40];    // K [pos][32ch], pitch 40
  __shared__ short Vt[32 * 264];    // V^T [ch][256pos], pitch 264
  __shared__ short Ps[64 * 264];    // exp(S) [qrow][256pos], pitch 264
  __shared__ float rsum[64];
  int lin = blockIdx.x;
  int vb = (lin >= 1280) ? 1 : 0;
  int r2 = lin - vb * 1280;         // 0..1279 = head*256 + s
  int head = r2 >> 8, s = r2 & 255;
  const bf16* Yq = Y + (size_t)vb * 31457280;
  const bf16* Yk = Yq + 10485760;
  const bf16* Yv = Yk + 10485760;
  int t = threadIdx.x, wv = t >> 6, l = t & 63;

  #pragma unroll
  for (int i = 0; i < 4; ++i) {     // stage K
    int u = t + i * 256;
    int pos = u >> 2, ch = u & 3;
    size_t pix = vb ? ((size_t)pos * 256 + s) : ((size_t)s * 256 + pos);
    short8 kv = *(const short8*)(Yk + pix * 160 + head * 32 + ch * 8);
    *(short8*)(Ks + pos * 40 + ch * 8) = kv;
  }
  #pragma unroll
  for (int i = 0; i < 2; ++i) {     // stage V transposed: pos-pairs, packed b32 writes
    int u = t + i * 256;
    int pp = u >> 2, ch = u & 3;    // pp: pos pair 0..127
    int pos0 = pp * 2;
    size_t pix0 = vb ? ((size_t)pos0 * 256 + s) : ((size_t)s * 256 + pos0);
    size_t pix1 = vb ? ((size_t)(pos0 + 1) * 256 + s) : ((size_t)s * 256 + pos0 + 1);
    short8 v0 = *(const short8*)(Yv + pix0 * 160 + head * 32 + ch * 8);
    short8 v1 = *(const short8*)(Yv + pix1 * 160 + head * 32 + ch * 8);
    #pragma unroll
    for (int j = 0; j < 8; ++j) {
      unsigned pack = (unsigned)(unsigned short)v0[j] | ((unsigned)(unsigned short)v1[j] << 16);
      *(unsigned*)(Vt + (ch * 8 + j) * 264 + pos0) = pack;   // pos0 even -> 4B aligned
    }
  }
  __syncthreads();

  for (int qb = 0; qb < 4; ++qb) {
    // Q B-fragment straight from global (L2-hot): lane holds Q[qrow=l&15][ch=(l>>4)*8+j]
    int qrow = qb * 64 + wv * 16 + (l & 15);
    size_t qpix = vb ? ((size_t)qrow * 256 + s) : ((size_t)s * 256 + qrow);
    short8 qf = *(const short8*)(Yq + qpix * 160 + head * 32 + (l >> 4) * 8);

    float psum = 0.f;
    #pragma unroll
    for (int mt = 0; mt < 16; ++mt) {  // S^T strip: 256 pos x 16 qrows per wave
      short8 kf = *(const short8*)(Ks + (mt * 16 + (l & 15)) * 40 + (l >> 4) * 8);
      floatx4 st = __builtin_amdgcn_mfma_f32_16x16x32_bf16(kf, qf, floatx4{0.f, 0.f, 0.f, 0.f}, 0, 0, 0);
      short4v pv;
      #pragma unroll
      for (int r = 0; r < 4; ++r) {    // scores are tiny (weights*0.02): exp w/o max-sub is safe
        float e = __expf(st[r]);
        psum += e;
        pv[r] = f2bs(e);
      }
      // lane holds S^T[pos=mt*16+(l>>4)*4+r][qrow=wv*16+(l&15)] -> contiguous 4-pos pack
      *(short4v*)(Ps + (wv * 16 + (l & 15)) * 264 + mt * 16 + (l >> 4) * 4) = pv;
    }
    psum += __shfl_xor(psum, 16);
    psum += __shfl_xor(psum, 32);
    if (l < 16) rsum[wv * 16 + l] = psum;
    __syncthreads();

    floatx4 oacc[2] = {floatx4{0.f, 0.f, 0.f, 0.f}, floatx4{0.f, 0.f, 0.f, 0.f}};
    #pragma unroll
    for (int kt = 0; kt < 8; ++kt) {
      short8 pf = *(const short8*)(Ps + (wv * 16 + (l & 15)) * 264 + kt * 32 + (l >> 4) * 8);
      #pragma unroll
      for (int nt = 0; nt < 2; ++nt) {
        short8 vf = *(const short8*)(Vt + (nt * 16 + (l & 15)) * 264 + kt * 32 + (l >> 4) * 8);
        oacc[nt] = __builtin_amdgcn_mfma_f32_16x16x32_bf16(pf, vf, oacc[nt], 0, 0, 0);
      }
    }
    floatx4 rs = *(const floatx4*)(rsum + wv * 16 + (l >> 4) * 4);
    #pragma unroll
    for (int nt = 0; nt < 2; ++nt) {
      int ch = head * 32 + nt * 16 + (l & 15);
      int p0 = qb * 64 + wv * 16 + (l >> 4) * 4;  // 4 consecutive positions
      if (vb == 0) {
        floatx4 o;
        #pragma unroll
        for (int r = 0; r < 4; ++r) o[r] = oacc[nt][r] / rs[r];
        *(floatx4*)(outF + (size_t)ch * 65536 + s * 256 + p0) = o;   // out[b][ch][h=s][w], fp32
      } else {
        short4v o;
        #pragma unroll
        for (int r = 0; r < 4; ++r) o[r] = f2bs(oacc[nt][r] / rs[r]);
        *(short4v*)(av + (size_t)s * 40960 + ch * 256 + p0) = o;     // av[s=w][ch][h], bf16
      }
    }
    __syncthreads();   // protect Ps/rsum reuse by next qb iteration
  }
}

// ---------------- v-branch layout fix: out[2+b][oc][h][w] = av[w][oc][h], bf16 -> fp32 ----------------
__global__ void k_trans(const bf16* __restrict__ av, float* __restrict__ outb) {
  __shared__ short tile[64 * 68];
  int oc = blockIdx.x, w0 = blockIdx.y * 64, h0 = blockIdx.z * 64;
  int t = threadIdx.x;
  #pragma unroll
  for (int i = 0; i < 2; ++i) {
    int u = t + i * 256;
    int w_i = u >> 3, hc = u & 7;
    short8 v = *(const short8*)(av + (size_t)(w0 + w_i) * 40960 + oc * 256 + h0 + hc * 8);
    short4v lo = {v[0], v[1], v[2], v[3]}, hi = {v[4], v[5], v[6], v[7]};
    *(short4v*)(tile + w_i * 68 + hc * 8) = lo;
    *(short4v*)(tile + w_i * 68 + hc * 8 + 4) = hi;
  }
  __syncthreads();
  #pragma unroll
  for (int i = 0; i < 2; ++i) {
    int u = t + i * 256;
    int h_i = u >> 3, wc = u & 7;
    float* orow = outb + (size_t)oc * 65536 + (h0 + h_i) * 256 + w0 + wc * 8;
    floatx4 o0, o1;
    #pragma unroll
    for (int j = 0; j < 4; ++j) o0[j] = s2f(tile[(wc * 8 + j) * 68 + h_i]);
    #pragma unroll
    for (int j = 0; j < 4; ++j) o1[j] = s2f(tile[(wc * 8 + 4 + j) * 68 + h_i]);
    *(floatx4*)(orow) = o0;
    *(floatx4*)(orow + 4) = o1;
  }
}

extern "C" void kernel_launch(void* const* d_in, const int* in_sizes, int n_in,
                              void* d_out, int out_size, void* d_ws, size_t ws_size,
                              hipStream_t stream) {
  (void)in_sizes; (void)n_in; (void)out_size; (void)ws_size;
  const float* x      = (const float*)d_in[0];
  const float* ln_w   = (const float*)d_in[1];
  const float* ln_b   = (const float*)d_in[2];
  const float* conv_w = (const float*)d_in[3];
  const float* conv_b = (const float*)d_in[4];
  float* outF = (float*)d_out;

  char* ws = (char*)d_ws;
  bf16*  Wc  = (bf16*)ws;                                   // 2*512*320 bf16 = 655360 B
  float* bc  = (float*)(ws + 655360);                       // 1024 f32   = 4096 B
  float* t2  = (float*)(ws + 659456);                       // 320 f32    (pad to 660736)
  bf16*  XnT = (bf16*)(ws + 660736);                        // 65536*320  = 41943040 B
  bf16*  Y   = (bf16*)(ws + 660736 + 41943040ULL);          // 2 br * 3 * 65536*160 = 125829120 B
  bf16*  av  = (bf16*)(ws + 660736 + 41943040ULL + 125829120ULL);  // 20971520 B

  k_t2<<<320, 64, 0, stream>>>(conv_w, conv_b, ln_b, t2);

  WcArgs wa;
  wa.conv_w = conv_w; wa.ln_w = ln_w; wa.t2 = t2; wa.Wc = Wc; wa.bc = bc;
  for (int br = 0; br < 2; ++br)
    for (int q = 0; q < 3; ++q) {
      wa.pw[br * 3 + q] = (const float*)d_in[5 + br * 6 + q * 2];
      wa.pb[br * 3 + q] = (const float*)d_in[6 + br * 6 + q * 2];
    }
  k_wc<<<1024, 64, 0, stream>>>(wa);

  for (int b = 0; b < 2; ++b) {
    k_xnt<<<1024, 256, 0, stream>>>(x, XnT, b);
    k_gemm<<<2048, 512, 0, stream>>>(Wc, bc, XnT, Y);
    k_attn<<<2560, 256, 0, stream>>>(Y, outF + (size_t)b * 160 * 65536, av);
    k_trans<<<dim3(160, 4, 4), 256, 0, stream>>>(av, outF + (size_t)(2 + b) * 160 * 65536);
  }
}